// Round 13
// baseline (341.451 us; speedup 1.0000x reference)
//
#include <hip/hip_runtime.h>
#include <math.h>

#define NN 50000
#define NE 800000
#define DIN 128
#define DH 64
#define NG 64

#define GEMM_BLOCKS ((NN + 63) / 64)     // 782
#define DEG_BLOCKS 2048
#define FILL_BLOCKS 2048
#define SCALE_BLOCKS 256
#define SCAN_BLOCKS ((NN + 255) / 256)   // 196
#define PULL_BLOCKS 2048
#define PULL_CHUNK ((NN + PULL_BLOCKS - 1) / PULL_BLOCKS)   // 25

// ---------------- hybrid: gemm layer1 (UNSCALED) + degree histogram ----------------
// Round-9 proven: deg half is resource-trivial, so hybrid is compatible.
template <int K>
__global__ __launch_bounds__(256, 4) void gemm_deg_kernel(const float* __restrict__ in,
                                                          const float* __restrict__ W,
                                                          float* __restrict__ out, int n,
                                                          const int* __restrict__ col,
                                                          int* __restrict__ indeg, int e) {
    __shared__ float Ws[K * 64];
    if (blockIdx.x >= GEMM_BLOCKS) {
        int i = (blockIdx.x - GEMM_BLOCKS) * 256 + threadIdx.x;
        int stride = DEG_BLOCKS * 256;
        for (; i < e; i += stride) atomicAdd(&indeg[col[i]], 1);
        return;
    }
    for (int t = threadIdx.x; t < K * 16; t += 256)
        reinterpret_cast<float4*>(Ws)[t] = reinterpret_cast<const float4*>(W)[t];
    __syncthreads();

    int w = threadIdx.x >> 6, l = threadIdx.x & 63;
    int fq = l & 15;
    int nl = l >> 4;
    int base = blockIdx.x * 64 + w * 16 + nl * 4;

    const float* r0 = in + (size_t)min(base + 0, n - 1) * K;
    const float* r1 = in + (size_t)min(base + 1, n - 1) * K;
    const float* r2 = in + (size_t)min(base + 2, n - 1) * K;
    const float* r3 = in + (size_t)min(base + 3, n - 1) * K;

    float acc[4][4];
    #pragma unroll
    for (int i = 0; i < 4; ++i)
        #pragma unroll
        for (int f = 0; f < 4; ++f) acc[i][f] = 0.f;

    #pragma unroll 2
    for (int k = 0; k < K; k += 4) {
        float4 wv[4];
        #pragma unroll
        for (int kk = 0; kk < 4; ++kk)
            wv[kk] = *reinterpret_cast<const float4*>(&Ws[(k + kk) * 64 + 4 * fq]);
        float4 xv[4];
        xv[0] = *reinterpret_cast<const float4*>(r0 + k);
        xv[1] = *reinterpret_cast<const float4*>(r1 + k);
        xv[2] = *reinterpret_cast<const float4*>(r2 + k);
        xv[3] = *reinterpret_cast<const float4*>(r3 + k);
        #pragma unroll
        for (int i = 0; i < 4; ++i) {
            float xs[4] = {xv[i].x, xv[i].y, xv[i].z, xv[i].w};
            #pragma unroll
            for (int kk = 0; kk < 4; ++kk) {
                acc[i][0] = fmaf(xs[kk], wv[kk].x, acc[i][0]);
                acc[i][1] = fmaf(xs[kk], wv[kk].y, acc[i][1]);
                acc[i][2] = fmaf(xs[kk], wv[kk].z, acc[i][2]);
                acc[i][3] = fmaf(xs[kk], wv[kk].w, acc[i][3]);
            }
        }
    }

    #pragma unroll
    for (int i = 0; i < 4; ++i) {
        int node = base + i;
        if (node < n) {
            float4 o = make_float4(acc[i][0], acc[i][1], acc[i][2], acc[i][3]);
            *reinterpret_cast<float4*>(&out[(size_t)node * 64 + 4 * fq]) = o;
        }
    }
}

// ---------------- 3-phase coalesced multi-block scan ----------------
__global__ __launch_bounds__(256) void scan_phaseA(const int* __restrict__ indeg,
                                                   int* __restrict__ partial, int n) {
    int i = blockIdx.x * 256 + threadIdx.x;
    int v = (i < n) ? indeg[i] : 0;
    int s = v;
    #pragma unroll
    for (int d = 1; d < 64; d <<= 1) s += __shfl_xor(s, d, 64);
    __shared__ int ws[4];
    if ((threadIdx.x & 63) == 0) ws[threadIdx.x >> 6] = s;
    __syncthreads();
    if (threadIdx.x == 0) partial[blockIdx.x] = ws[0] + ws[1] + ws[2] + ws[3];
}

__global__ __launch_bounds__(256) void scan_phaseB(int* __restrict__ partial, int nb) {
    int t = threadIdx.x;
    int lane = t & 63, wid = t >> 6;
    int v = (t < nb) ? partial[t] : 0;
    int inc = v;
    #pragma unroll
    for (int d = 1; d < 64; d <<= 1) {
        int u = __shfl_up(inc, d, 64);
        if (lane >= d) inc += u;
    }
    __shared__ int ws[4];
    if (lane == 63) ws[wid] = inc;
    __syncthreads();
    int woff = 0;
    #pragma unroll
    for (int k = 0; k < 4; ++k) woff += (k < wid) ? ws[k] : 0;
    if (t < nb) partial[t] = woff + inc - v;   // exclusive
}

__global__ __launch_bounds__(256) void scan_phaseC(const int* __restrict__ indeg,
                                                   const int* __restrict__ partial,
                                                   int* __restrict__ off,
                                                   int* __restrict__ cursor,
                                                   float* __restrict__ dinv, int n) {
    int i = blockIdx.x * 256 + threadIdx.x;
    int d = (i < n) ? indeg[i] : 0;
    int lane = threadIdx.x & 63, wid = threadIdx.x >> 6;
    int inc = d;
    #pragma unroll
    for (int dd = 1; dd < 64; dd <<= 1) {
        int u = __shfl_up(inc, dd, 64);
        if (lane >= dd) inc += u;
    }
    __shared__ int ws[4];
    if (lane == 63) ws[wid] = inc;
    __syncthreads();
    int woff = 0;
    #pragma unroll
    for (int k = 0; k < 4; ++k) woff += (k < wid) ? ws[k] : 0;
    int excl = partial[blockIdx.x] + woff + inc - d;
    if (i < n) {
        off[i] = excl;
        cursor[i] = excl;
        dinv[i] = rsqrtf((float)(d + 1));
        if (i == n - 1) off[n] = excl + d;
    }
}

// ---------------- hybrid: layer-1 scale (FIRST, overlaps) + CSR fill ----------------
// Round-11 lesson: scale blocks appended AFTER fill tail-serialized (+11us).
// Scale blocks first -> they run concurrent with early fill blocks.
__global__ __launch_bounds__(256) void fill_scale_kernel(const int* __restrict__ row,
                                                         const int* __restrict__ col,
                                                         int* __restrict__ cursor,
                                                         int* __restrict__ ews, int e,
                                                         float* __restrict__ tmp,
                                                         const float* __restrict__ dinv,
                                                         int n4) {
    if (blockIdx.x < SCALE_BLOCKS) {
        float4* t4 = reinterpret_cast<float4*>(tmp);
        int i = blockIdx.x * 256 + threadIdx.x;
        int stride = SCALE_BLOCKS * 256;
        for (; i < n4; i += stride) {
            float sc = dinv[i >> 4];
            float4 v = t4[i];
            v.x *= sc; v.y *= sc; v.z *= sc; v.w *= sc;
            t4[i] = v;
        }
    } else {
        int i = (blockIdx.x - SCALE_BLOCKS) * 256 + threadIdx.x;
        int stride = FILL_BLOCKS * 256;
        for (; i < e; i += stride) {
            int c = col[i];
            int p = atomicAdd(&cursor[c], 1);
            ews[p] = row[i];
        }
    }
}

// ---------------- fused pull + next-layer GEMM ----------------
// wave = 1 node (grid-stride over a contiguous chunk). Gather-sum of pre-scaled
// t rows; after the e4 xor-reduce ALL 64 lanes hold the full reduced float4, so
// h = ELU((sum+self)*dt + b) is wave-replicated. The next GEMM is then in-wave:
// lane j caches W_next column j in 64 VGPRs (loaded once per wave, amortized
// over ~6 nodes), h broadcast via 64 shfl + 64 FMA; t_next = (h@Wn)*dinv[node].
// Eliminates standalone gemm2/gemm3 + h round-trips.
__global__ __launch_bounds__(256, 4) void pull_gemm_kernel(const float* __restrict__ tin,
                                                           const int* __restrict__ off,
                                                           const int* __restrict__ ews,
                                                           const float* __restrict__ dinv,
                                                           const float* __restrict__ bias,
                                                           const float* __restrict__ Wn,
                                                           float* __restrict__ tout, int n) {
    int wid = threadIdx.x >> 6;
    int lane = threadIdx.x & 63;
    int fg = lane & 15, e4 = lane >> 4;

    float Wcol[64];
    #pragma unroll
    for (int k = 0; k < 64; ++k) Wcol[k] = Wn[k * 64 + lane];

    const float4* trow = reinterpret_cast<const float4*>(tin);
    float4 b4 = reinterpret_cast<const float4*>(bias)[fg];

    int lo = blockIdx.x * PULL_CHUNK;
    int hi = lo + PULL_CHUNK; if (hi > n) hi = n;

    for (int node = lo + wid; node < hi; node += 4) {
        float4 acc = make_float4(0.f, 0.f, 0.f, 0.f);
        int e = off[node], s1 = off[node + 1];
        for (; e + 8 <= s1; e += 8) {
            int i0 = ews[e + e4];
            int i1 = ews[e + 4 + e4];
            float4 v0 = trow[(size_t)i0 * 16 + fg];
            float4 v1 = trow[(size_t)i1 * 16 + fg];
            acc.x += v0.x + v1.x;
            acc.y += v0.y + v1.y;
            acc.z += v0.z + v1.z;
            acc.w += v0.w + v1.w;
        }
        for (; e < s1; e += 4) {
            int idx = e + e4;
            if (idx < s1) {
                float4 v = trow[(size_t)ews[idx] * 16 + fg];
                acc.x += v.x; acc.y += v.y; acc.z += v.z; acc.w += v.w;
            }
        }
        acc.x += __shfl_xor(acc.x, 16, 64);
        acc.y += __shfl_xor(acc.y, 16, 64);
        acc.z += __shfl_xor(acc.z, 16, 64);
        acc.w += __shfl_xor(acc.w, 16, 64);
        acc.x += __shfl_xor(acc.x, 32, 64);
        acc.y += __shfl_xor(acc.y, 32, 64);
        acc.z += __shfl_xor(acc.z, 32, 64);
        acc.w += __shfl_xor(acc.w, 32, 64);

        float dt = dinv[node];
        float4 self = trow[(size_t)node * 16 + fg];
        float4 r;
        r.x = fmaf(acc.x + self.x, dt, b4.x);
        r.y = fmaf(acc.y + self.y, dt, b4.y);
        r.z = fmaf(acc.z + self.z, dt, b4.z);
        r.w = fmaf(acc.w + self.w, dt, b4.w);
        r.x = (r.x > 0.f) ? r.x : expm1f(r.x);
        r.y = (r.y > 0.f) ? r.y : expm1f(r.y);
        r.z = (r.z > 0.f) ? r.z : expm1f(r.z);
        r.w = (r.w > 0.f) ? r.w : expm1f(r.w);

        // in-wave GEMM: out_j = sum_k h_k * Wn[k][j], j = lane
        float o = 0.f;
        #pragma unroll
        for (int q = 0; q < 16; ++q) {
            float hx = __shfl(r.x, q, 64);
            float hy = __shfl(r.y, q, 64);
            float hz = __shfl(r.z, q, 64);
            float hw = __shfl(r.w, q, 64);
            o = fmaf(hx, Wcol[4 * q + 0], o);
            o = fmaf(hy, Wcol[4 * q + 1], o);
            o = fmaf(hz, Wcol[4 * q + 2], o);
            o = fmaf(hw, Wcol[4 * q + 3], o);
        }
        tout[(size_t)node * 64 + lane] = o * dt;
    }
}

// ---------------- fused pull + final linear + mean-pool partials ----------------
__global__ __launch_bounds__(256, 4) void pull_final_kernel(const float* __restrict__ tin,
                                                            const int* __restrict__ off,
                                                            const int* __restrict__ ews,
                                                            const float* __restrict__ dinv,
                                                            const float* __restrict__ bias,
                                                            const float* __restrict__ Wl,
                                                            const int* __restrict__ batch,
                                                            float* __restrict__ gsum,
                                                            float* __restrict__ gcnt, int n) {
    __shared__ float lsum[NG];
    __shared__ float lcnt[NG];
    if (threadIdx.x < NG) { lsum[threadIdx.x] = 0.f; lcnt[threadIdx.x] = 0.f; }
    __syncthreads();

    int wid = threadIdx.x >> 6;
    int lane = threadIdx.x & 63;
    int fg = lane & 15, e4 = lane >> 4;
    const float4* trow = reinterpret_cast<const float4*>(tin);
    float4 b4 = reinterpret_cast<const float4*>(bias)[fg];
    float4 wl4 = reinterpret_cast<const float4*>(Wl)[fg];

    int lo = blockIdx.x * PULL_CHUNK;
    int hi = lo + PULL_CHUNK; if (hi > n) hi = n;

    for (int node = lo + wid; node < hi; node += 4) {
        float4 acc = make_float4(0.f, 0.f, 0.f, 0.f);
        int e = off[node], s1 = off[node + 1];
        for (; e + 8 <= s1; e += 8) {
            int i0 = ews[e + e4];
            int i1 = ews[e + 4 + e4];
            float4 v0 = trow[(size_t)i0 * 16 + fg];
            float4 v1 = trow[(size_t)i1 * 16 + fg];
            acc.x += v0.x + v1.x;
            acc.y += v0.y + v1.y;
            acc.z += v0.z + v1.z;
            acc.w += v0.w + v1.w;
        }
        for (; e < s1; e += 4) {
            int idx = e + e4;
            if (idx < s1) {
                float4 v = trow[(size_t)ews[idx] * 16 + fg];
                acc.x += v.x; acc.y += v.y; acc.z += v.z; acc.w += v.w;
            }
        }
        acc.x += __shfl_xor(acc.x, 16, 64);
        acc.y += __shfl_xor(acc.y, 16, 64);
        acc.z += __shfl_xor(acc.z, 16, 64);
        acc.w += __shfl_xor(acc.w, 16, 64);
        acc.x += __shfl_xor(acc.x, 32, 64);
        acc.y += __shfl_xor(acc.y, 32, 64);
        acc.z += __shfl_xor(acc.z, 32, 64);
        acc.w += __shfl_xor(acc.w, 32, 64);

        float dt = dinv[node];
        float4 self = trow[(size_t)node * 16 + fg];
        float4 r;
        r.x = fmaf(acc.x + self.x, dt, b4.x);
        r.y = fmaf(acc.y + self.y, dt, b4.y);
        r.z = fmaf(acc.z + self.z, dt, b4.z);
        r.w = fmaf(acc.w + self.w, dt, b4.w);
        r.x = (r.x > 0.f) ? r.x : expm1f(r.x);
        r.y = (r.y > 0.f) ? r.y : expm1f(r.y);
        r.z = (r.z > 0.f) ? r.z : expm1f(r.z);
        r.w = (r.w > 0.f) ? r.w : expm1f(r.w);

        // dot(h, Wl): per-lane partial over its 4 features, reduce over fg
        float p = r.x * wl4.x + r.y * wl4.y + r.z * wl4.z + r.w * wl4.w;
        p += __shfl_xor(p, 1, 64);
        p += __shfl_xor(p, 2, 64);
        p += __shfl_xor(p, 4, 64);
        p += __shfl_xor(p, 8, 64);
        if (lane == 0) {
            int g = batch[node];
            atomicAdd(&lsum[g], p);
            atomicAdd(&lcnt[g], 1.f);
        }
    }
    __syncthreads();
    if (threadIdx.x < NG && lcnt[threadIdx.x] != 0.f) {
        atomicAdd(&gsum[threadIdx.x], lsum[threadIdx.x]);
        atomicAdd(&gcnt[threadIdx.x], lcnt[threadIdx.x]);
    }
}

__global__ void pool_div_kernel(const float* __restrict__ gsum, const float* __restrict__ gcnt,
                                const float* __restrict__ bl, float* __restrict__ out) {
    int g = threadIdx.x;
    if (g < NG) {
        float c = gcnt[g];
        out[g] = (c > 0.5f) ? (gsum[g] / c + bl[0]) : 0.f;
    }
}

extern "C" void kernel_launch(void* const* d_in, const int* in_sizes, int n_in,
                              void* d_out, int out_size, void* d_ws, size_t ws_size,
                              hipStream_t stream) {
    const float* x    = (const float*)d_in[0];
    const int*   eidx = (const int*)d_in[1];
    const int*   row  = eidx;              // edge_index[0] = sources
    const int*   col  = eidx + NE;         // edge_index[1] = targets
    const int*   batch = (const int*)d_in[2];
    const float* W1 = (const float*)d_in[3];
    const float* b1 = (const float*)d_in[4];
    const float* W2 = (const float*)d_in[5];
    const float* b2 = (const float*)d_in[6];
    const float* W3 = (const float*)d_in[7];
    const float* b3 = (const float*)d_in[8];
    const float* Wl = (const float*)d_in[9];
    const float* bl = (const float*)d_in[10];
    float* out = (float*)d_out;

    // workspace layout (all offsets 64-element = 256B aligned)
    size_t cur = 0;
    auto take = [&](size_t elems) { size_t c = cur; cur += (elems + 63) & ~(size_t)63; return c; };
    float* base_f = (float*)d_ws;
    int*   base_i = (int*)d_ws;

    float*  dinv    = base_f + take(NN);
    int*    indeg   = base_i + take(NN);
    int*    csr_off = base_i + take(NN + 1);
    int*    cursor  = base_i + take(NN);
    int*    partial = base_i + take(SCAN_BLOCKS);
    int*    ews     = base_i + take(NE);
    float*  tA      = base_f + take((size_t)NN * 64);
    float*  tB      = base_f + take((size_t)NN * 64);
    float*  gg      = base_f + take(2 * NG);   // gsum | gcnt contiguous
    float*  gsum    = gg;
    float*  gcnt    = gg + NG;
    (void)ws_size; (void)n_in; (void)in_sizes; (void)out_size;

    hipMemsetAsync(indeg, 0, NN * sizeof(int), stream);
    hipMemsetAsync(gg, 0, 2 * NG * sizeof(float), stream);

    // ---- layer-1 GEMM (unscaled) fused with degree histogram ----
    gemm_deg_kernel<DIN><<<GEMM_BLOCKS + DEG_BLOCKS, 256, 0, stream>>>(
        x, W1, tA, NN, col, indeg, NE);
    // ---- coalesced 3-phase scan (+ dinv/cursor fused into phase C) ----
    scan_phaseA<<<SCAN_BLOCKS, 256, 0, stream>>>(indeg, partial, NN);
    scan_phaseB<<<1, 256, 0, stream>>>(partial, SCAN_BLOCKS);
    scan_phaseC<<<SCAN_BLOCKS, 256, 0, stream>>>(indeg, partial, csr_off, cursor, dinv, NN);
    // ---- layer-1 dinv scale (first) + CSR fill hybrid ----
    fill_scale_kernel<<<SCALE_BLOCKS + FILL_BLOCKS, 256, 0, stream>>>(
        row, col, cursor, ews, NE, tA, dinv, NN * 16);

    // ---- layer 1 pull + layer-2 GEMM (fused) : tA -> tB ----
    pull_gemm_kernel<<<PULL_BLOCKS, 256, 0, stream>>>(
        tA, csr_off, ews, dinv, b1, W2, tB, NN);
    // ---- layer 2 pull + layer-3 GEMM (fused) : tB -> tA ----
    pull_gemm_kernel<<<PULL_BLOCKS, 256, 0, stream>>>(
        tB, csr_off, ews, dinv, b2, W3, tA, NN);
    // ---- layer 3 pull + final linear + mean-pool partials (fused) ----
    pull_final_kernel<<<PULL_BLOCKS, 256, 0, stream>>>(
        tA, csr_off, ews, dinv, b3, Wl, batch, gsum, gcnt, NN);

    pool_div_kernel<<<1, 64, 0, stream>>>(gsum, gcnt, bl, out);
}

// Round 14
// 330.266 us; speedup vs baseline: 1.0339x; 1.0339x over previous
//
#include <hip/hip_runtime.h>
#include <math.h>

#define NN 50000
#define NE 800000
#define DIN 128
#define DH 64
#define NG 64

#define GEMM_BLOCKS ((NN + 63) / 64)     // 782
#define DEG_BLOCKS 2048
#define FILL_BLOCKS 2048
#define SCAN_BLOCKS ((NN + 255) / 256)   // 196

// ---------------- hybrid: gemm layer1 + degree histogram (round-9 proven, 333.7us) ----------------
template <int K>
__global__ __launch_bounds__(256, 4) void gemm_deg_kernel(const float* __restrict__ in,
                                                          const float* __restrict__ W,
                                                          float* __restrict__ out, int n,
                                                          const int* __restrict__ col,
                                                          int* __restrict__ indeg, int e) {
    __shared__ float Ws[K * 64];
    if (blockIdx.x >= GEMM_BLOCKS) {
        int i = (blockIdx.x - GEMM_BLOCKS) * 256 + threadIdx.x;
        int stride = DEG_BLOCKS * 256;
        for (; i < e; i += stride) atomicAdd(&indeg[col[i]], 1);
        return;
    }
    for (int t = threadIdx.x; t < K * 16; t += 256)
        reinterpret_cast<float4*>(Ws)[t] = reinterpret_cast<const float4*>(W)[t];
    __syncthreads();

    int w = threadIdx.x >> 6, l = threadIdx.x & 63;
    int fq = l & 15;
    int nl = l >> 4;
    int base = blockIdx.x * 64 + w * 16 + nl * 4;

    const float* r0 = in + (size_t)min(base + 0, n - 1) * K;
    const float* r1 = in + (size_t)min(base + 1, n - 1) * K;
    const float* r2 = in + (size_t)min(base + 2, n - 1) * K;
    const float* r3 = in + (size_t)min(base + 3, n - 1) * K;

    float acc[4][4];
    #pragma unroll
    for (int i = 0; i < 4; ++i)
        #pragma unroll
        for (int f = 0; f < 4; ++f) acc[i][f] = 0.f;

    #pragma unroll 2
    for (int k = 0; k < K; k += 4) {
        float4 wv[4];
        #pragma unroll
        for (int kk = 0; kk < 4; ++kk)
            wv[kk] = *reinterpret_cast<const float4*>(&Ws[(k + kk) * 64 + 4 * fq]);
        float4 xv[4];
        xv[0] = *reinterpret_cast<const float4*>(r0 + k);
        xv[1] = *reinterpret_cast<const float4*>(r1 + k);
        xv[2] = *reinterpret_cast<const float4*>(r2 + k);
        xv[3] = *reinterpret_cast<const float4*>(r3 + k);
        #pragma unroll
        for (int i = 0; i < 4; ++i) {
            float xs[4] = {xv[i].x, xv[i].y, xv[i].z, xv[i].w};
            #pragma unroll
            for (int kk = 0; kk < 4; ++kk) {
                acc[i][0] = fmaf(xs[kk], wv[kk].x, acc[i][0]);
                acc[i][1] = fmaf(xs[kk], wv[kk].y, acc[i][1]);
                acc[i][2] = fmaf(xs[kk], wv[kk].z, acc[i][2]);
                acc[i][3] = fmaf(xs[kk], wv[kk].w, acc[i][3]);
            }
        }
    }

    #pragma unroll
    for (int i = 0; i < 4; ++i) {
        int node = base + i;
        if (node < n) {
            float4 o = make_float4(acc[i][0], acc[i][1], acc[i][2], acc[i][3]);
            *reinterpret_cast<float4*>(&out[(size_t)node * 64 + 4 * fq]) = o;
        }
    }
}

// ---------------- GEMM (layers 2,3) — round-9 proven ----------------
template <int K>
__global__ __launch_bounds__(256, 4) void gemm_kernel(const float* __restrict__ in,
                                                      const float* __restrict__ W,
                                                      float* __restrict__ out, int n) {
    __shared__ float Ws[K * 64];
    for (int t = threadIdx.x; t < K * 16; t += 256)
        reinterpret_cast<float4*>(Ws)[t] = reinterpret_cast<const float4*>(W)[t];
    __syncthreads();

    int w = threadIdx.x >> 6, l = threadIdx.x & 63;
    int fq = l & 15;
    int nl = l >> 4;
    int base = blockIdx.x * 64 + w * 16 + nl * 4;

    const float* r0 = in + (size_t)min(base + 0, n - 1) * K;
    const float* r1 = in + (size_t)min(base + 1, n - 1) * K;
    const float* r2 = in + (size_t)min(base + 2, n - 1) * K;
    const float* r3 = in + (size_t)min(base + 3, n - 1) * K;

    float acc[4][4];
    #pragma unroll
    for (int i = 0; i < 4; ++i)
        #pragma unroll
        for (int f = 0; f < 4; ++f) acc[i][f] = 0.f;

    #pragma unroll 2
    for (int k = 0; k < K; k += 4) {
        float4 wv[4];
        #pragma unroll
        for (int kk = 0; kk < 4; ++kk)
            wv[kk] = *reinterpret_cast<const float4*>(&Ws[(k + kk) * 64 + 4 * fq]);
        float4 xv[4];
        xv[0] = *reinterpret_cast<const float4*>(r0 + k);
        xv[1] = *reinterpret_cast<const float4*>(r1 + k);
        xv[2] = *reinterpret_cast<const float4*>(r2 + k);
        xv[3] = *reinterpret_cast<const float4*>(r3 + k);
        #pragma unroll
        for (int i = 0; i < 4; ++i) {
            float xs[4] = {xv[i].x, xv[i].y, xv[i].z, xv[i].w};
            #pragma unroll
            for (int kk = 0; kk < 4; ++kk) {
                acc[i][0] = fmaf(xs[kk], wv[kk].x, acc[i][0]);
                acc[i][1] = fmaf(xs[kk], wv[kk].y, acc[i][1]);
                acc[i][2] = fmaf(xs[kk], wv[kk].z, acc[i][2]);
                acc[i][3] = fmaf(xs[kk], wv[kk].w, acc[i][3]);
            }
        }
    }

    #pragma unroll
    for (int i = 0; i < 4; ++i) {
        int node = base + i;
        if (node < n) {
            float4 o = make_float4(acc[i][0], acc[i][1], acc[i][2], acc[i][3]);
            *reinterpret_cast<float4*>(&out[(size_t)node * 64 + 4 * fq]) = o;
        }
    }
}

// ---------------- 3-phase coalesced multi-block scan ----------------
__global__ __launch_bounds__(256) void scan_phaseA(const int* __restrict__ indeg,
                                                   int* __restrict__ partial, int n) {
    int i = blockIdx.x * 256 + threadIdx.x;
    int v = (i < n) ? indeg[i] : 0;
    int s = v;
    #pragma unroll
    for (int d = 1; d < 64; d <<= 1) s += __shfl_xor(s, d, 64);
    __shared__ int ws[4];
    if ((threadIdx.x & 63) == 0) ws[threadIdx.x >> 6] = s;
    __syncthreads();
    if (threadIdx.x == 0) partial[blockIdx.x] = ws[0] + ws[1] + ws[2] + ws[3];
}

__global__ __launch_bounds__(256) void scan_phaseB(int* __restrict__ partial, int nb) {
    int t = threadIdx.x;
    int lane = t & 63, wid = t >> 6;
    int v = (t < nb) ? partial[t] : 0;
    int inc = v;
    #pragma unroll
    for (int d = 1; d < 64; d <<= 1) {
        int u = __shfl_up(inc, d, 64);
        if (lane >= d) inc += u;
    }
    __shared__ int ws[4];
    if (lane == 63) ws[wid] = inc;
    __syncthreads();
    int woff = 0;
    #pragma unroll
    for (int k = 0; k < 4; ++k) woff += (k < wid) ? ws[k] : 0;
    if (t < nb) partial[t] = woff + inc - v;   // exclusive
}

__global__ __launch_bounds__(256) void scan_phaseC(const int* __restrict__ indeg,
                                                   const int* __restrict__ partial,
                                                   int* __restrict__ off,
                                                   int* __restrict__ cursor,
                                                   float* __restrict__ dinv, int n) {
    int i = blockIdx.x * 256 + threadIdx.x;
    int d = (i < n) ? indeg[i] : 0;
    int lane = threadIdx.x & 63, wid = threadIdx.x >> 6;
    int inc = d;
    #pragma unroll
    for (int dd = 1; dd < 64; dd <<= 1) {
        int u = __shfl_up(inc, dd, 64);
        if (lane >= dd) inc += u;
    }
    __shared__ int ws[4];
    if (lane == 63) ws[wid] = inc;
    __syncthreads();
    int woff = 0;
    #pragma unroll
    for (int k = 0; k < 4; ++k) woff += (k < wid) ? ws[k] : 0;
    int excl = partial[blockIdx.x] + woff + inc - d;
    if (i < n) {
        off[i] = excl;
        cursor[i] = excl;
        dinv[i] = rsqrtf((float)(d + 1));
        if (i == n - 1) off[n] = excl + d;
    }
}

// bucket edges by target: ew[p] = { bitcast(src), dinv[src]*dinv[col] } (round-9 proven)
__global__ void fill_kernel(const int* __restrict__ row, const int* __restrict__ col,
                            const float* __restrict__ dinv, int* __restrict__ cursor,
                            float2* __restrict__ ew, int e) {
    int i = blockIdx.x * blockDim.x + threadIdx.x;
    int stride = gridDim.x * blockDim.x;
    for (; i < e; i += stride) {
        int c = col[i], r = row[i];
        int p = atomicAdd(&cursor[c], 1);
        ew[p] = make_float2(__int_as_float(r), dinv[r] * dinv[c]);
    }
}

// ---------------- pull aggregation + bias + ELU ----------------
// Round-14 change (single variable vs round-9): 16 edges in flight per loop
// iteration (4 grouped metadata loads -> 4 grouped float4 gathers -> consume)
// instead of 8. Collapses the dependent ews->gather latency rounds per node
// (avg deg 17) from ~2-3 to ~1-2. Everything else identical to round 9.
__global__ __launch_bounds__(256) void pull_kernel(const float* __restrict__ tmp,
                                                   const int* __restrict__ off,
                                                   const float2* __restrict__ ew,
                                                   const float* __restrict__ dinv,
                                                   const float* __restrict__ bias,
                                                   float* __restrict__ out, int n) {
    int wid = threadIdx.x >> 6;
    int lane = threadIdx.x & 63;
    int node = blockIdx.x * 4 + wid;
    if (node >= n) return;
    int fg = lane & 15, e4 = lane >> 4;
    const float4* trow = reinterpret_cast<const float4*>(tmp);

    float4 acc = make_float4(0.f, 0.f, 0.f, 0.f);
    int e = off[node], s1 = off[node + 1];

    // 16 edges in flight: 4 metadata + 4 gathers issued as groups
    for (; e + 16 <= s1; e += 16) {
        float2 m0 = ew[e + e4];
        float2 m1 = ew[e + 4 + e4];
        float2 m2 = ew[e + 8 + e4];
        float2 m3 = ew[e + 12 + e4];
        float4 v0 = trow[(size_t)__float_as_int(m0.x) * 16 + fg];
        float4 v1 = trow[(size_t)__float_as_int(m1.x) * 16 + fg];
        float4 v2 = trow[(size_t)__float_as_int(m2.x) * 16 + fg];
        float4 v3 = trow[(size_t)__float_as_int(m3.x) * 16 + fg];
        acc.x = fmaf(v0.x, m0.y, acc.x);
        acc.y = fmaf(v0.y, m0.y, acc.y);
        acc.z = fmaf(v0.z, m0.y, acc.z);
        acc.w = fmaf(v0.w, m0.y, acc.w);
        acc.x = fmaf(v1.x, m1.y, acc.x);
        acc.y = fmaf(v1.y, m1.y, acc.y);
        acc.z = fmaf(v1.z, m1.y, acc.z);
        acc.w = fmaf(v1.w, m1.y, acc.w);
        acc.x = fmaf(v2.x, m2.y, acc.x);
        acc.y = fmaf(v2.y, m2.y, acc.y);
        acc.z = fmaf(v2.z, m2.y, acc.z);
        acc.w = fmaf(v2.w, m2.y, acc.w);
        acc.x = fmaf(v3.x, m3.y, acc.x);
        acc.y = fmaf(v3.y, m3.y, acc.y);
        acc.z = fmaf(v3.z, m3.y, acc.z);
        acc.w = fmaf(v3.w, m3.y, acc.w);
    }
    for (; e + 8 <= s1; e += 8) {
        float2 m0 = ew[e + e4];
        float2 m1 = ew[e + 4 + e4];
        float4 v0 = trow[(size_t)__float_as_int(m0.x) * 16 + fg];
        float4 v1 = trow[(size_t)__float_as_int(m1.x) * 16 + fg];
        acc.x = fmaf(v0.x, m0.y, acc.x);
        acc.y = fmaf(v0.y, m0.y, acc.y);
        acc.z = fmaf(v0.z, m0.y, acc.z);
        acc.w = fmaf(v0.w, m0.y, acc.w);
        acc.x = fmaf(v1.x, m1.y, acc.x);
        acc.y = fmaf(v1.y, m1.y, acc.y);
        acc.z = fmaf(v1.z, m1.y, acc.z);
        acc.w = fmaf(v1.w, m1.y, acc.w);
    }
    for (; e < s1; e += 4) {
        int idx = e + e4;
        if (idx < s1) {
            float2 m = ew[idx];
            float4 v = trow[(size_t)__float_as_int(m.x) * 16 + fg];
            acc.x = fmaf(v.x, m.y, acc.x);
            acc.y = fmaf(v.y, m.y, acc.y);
            acc.z = fmaf(v.z, m.y, acc.z);
            acc.w = fmaf(v.w, m.y, acc.w);
        }
    }

    // reduce over e4
    acc.x += __shfl_xor(acc.x, 16, 64);
    acc.y += __shfl_xor(acc.y, 16, 64);
    acc.z += __shfl_xor(acc.z, 16, 64);
    acc.w += __shfl_xor(acc.w, 16, 64);
    acc.x += __shfl_xor(acc.x, 32, 64);
    acc.y += __shfl_xor(acc.y, 32, 64);
    acc.z += __shfl_xor(acc.z, 32, 64);
    acc.w += __shfl_xor(acc.w, 32, 64);

    float dt = dinv[node];
    float s2 = dt * dt;
    float4 self = trow[(size_t)node * 16 + fg];
    float4 b4 = reinterpret_cast<const float4*>(bias)[fg];
    float4 r;
    r.x = acc.x + self.x * s2 + b4.x;
    r.y = acc.y + self.y * s2 + b4.y;
    r.z = acc.z + self.z * s2 + b4.z;
    r.w = acc.w + self.w * s2 + b4.w;
    r.x = (r.x > 0.f) ? r.x : expm1f(r.x);
    r.y = (r.y > 0.f) ? r.y : expm1f(r.y);
    r.z = (r.z > 0.f) ? r.z : expm1f(r.z);
    r.w = (r.w > 0.f) ? r.w : expm1f(r.w);
    if (e4 == 0)
        reinterpret_cast<float4*>(out)[(size_t)node * 16 + fg] = r;
}

// ---------------- final linear + grouped mean-pool partials ----------------
#define POOL_BLOCKS 256
__global__ __launch_bounds__(256) void final_pool_kernel(const float* __restrict__ h,
                                                         const float* __restrict__ Wl,
                                                         const int* __restrict__ batch,
                                                         float* __restrict__ gsum,
                                                         float* __restrict__ gcnt, int n) {
    __shared__ float lsum[NG];
    __shared__ float lcnt[NG];
    if (threadIdx.x < NG) { lsum[threadIdx.x] = 0.f; lcnt[threadIdx.x] = 0.f; }
    __syncthreads();
    int wid = threadIdx.x >> 6, lane = threadIdx.x & 63;
    float wl = Wl[lane];
    int per_block = (n + POOL_BLOCKS - 1) / POOL_BLOCKS;
    int start = blockIdx.x * per_block;
    int end = start + per_block;
    if (end > n) end = n;
    for (int node = start + wid; node < end; node += 4) {
        float p = h[(size_t)node * 64 + lane] * wl;
        #pragma unroll
        for (int d = 32; d >= 1; d >>= 1) p += __shfl_xor(p, d, 64);
        if (lane == 0) {
            int g = batch[node];
            atomicAdd(&lsum[g], p);
            atomicAdd(&lcnt[g], 1.f);
        }
    }
    __syncthreads();
    if (threadIdx.x < NG && lcnt[threadIdx.x] != 0.f) {
        atomicAdd(&gsum[threadIdx.x], lsum[threadIdx.x]);
        atomicAdd(&gcnt[threadIdx.x], lcnt[threadIdx.x]);
    }
}

__global__ void pool_div_kernel(const float* __restrict__ gsum, const float* __restrict__ gcnt,
                                const float* __restrict__ bl, float* __restrict__ out) {
    int g = threadIdx.x;
    if (g < NG) {
        float c = gcnt[g];
        out[g] = (c > 0.5f) ? (gsum[g] / c + bl[0]) : 0.f;
    }
}

extern "C" void kernel_launch(void* const* d_in, const int* in_sizes, int n_in,
                              void* d_out, int out_size, void* d_ws, size_t ws_size,
                              hipStream_t stream) {
    const float* x    = (const float*)d_in[0];
    const int*   eidx = (const int*)d_in[1];
    const int*   row  = eidx;              // edge_index[0] = sources
    const int*   col  = eidx + NE;         // edge_index[1] = targets
    const int*   batch = (const int*)d_in[2];
    const float* W1 = (const float*)d_in[3];
    const float* b1 = (const float*)d_in[4];
    const float* W2 = (const float*)d_in[5];
    const float* b2 = (const float*)d_in[6];
    const float* W3 = (const float*)d_in[7];
    const float* b3 = (const float*)d_in[8];
    const float* Wl = (const float*)d_in[9];
    const float* bl = (const float*)d_in[10];
    float* out = (float*)d_out;

    // workspace layout (all offsets 64-element = 256B aligned)
    size_t cur = 0;
    auto take = [&](size_t elems) { size_t c = cur; cur += (elems + 63) & ~(size_t)63; return c; };
    float* base_f = (float*)d_ws;
    int*   base_i = (int*)d_ws;

    float*  dinv    = base_f + take(NN);
    int*    indeg   = base_i + take(NN);
    int*    csr_off = base_i + take(NN + 1);
    int*    cursor  = base_i + take(NN);
    int*    partial = base_i + take(SCAN_BLOCKS);
    float2* ew      = (float2*)(base_f + take((size_t)NE * 2));
    float*  tmp     = base_f + take((size_t)NN * 64);
    float*  h       = base_f + take((size_t)NN * 64);
    float*  gg      = base_f + take(2 * NG);   // gsum | gcnt contiguous
    float*  gsum    = gg;
    float*  gcnt    = gg + NG;
    (void)ws_size; (void)n_in; (void)in_sizes; (void)out_size;

    hipMemsetAsync(indeg, 0, NN * sizeof(int), stream);
    hipMemsetAsync(gg, 0, 2 * NG * sizeof(float), stream);

    const int nblk_pull = (NN + 3) / 4;

    // ---- layer-1 GEMM fused with degree histogram (independent) ----
    gemm_deg_kernel<DIN><<<GEMM_BLOCKS + DEG_BLOCKS, 256, 0, stream>>>(
        x, W1, tmp, NN, col, indeg, NE);
    // ---- coalesced 3-phase scan (+ dinv/cursor fused into phase C) ----
    scan_phaseA<<<SCAN_BLOCKS, 256, 0, stream>>>(indeg, partial, NN);
    scan_phaseB<<<1, 256, 0, stream>>>(partial, SCAN_BLOCKS);
    scan_phaseC<<<SCAN_BLOCKS, 256, 0, stream>>>(indeg, partial, csr_off, cursor, dinv, NN);
    // ---- CSR fill ----
    fill_kernel<<<FILL_BLOCKS, 256, 0, stream>>>(row, col, dinv, cursor, ew, NE);

    // ---- layer 1 pull ----
    pull_kernel<<<nblk_pull, 256, 0, stream>>>(tmp, csr_off, ew, dinv, b1, h, NN);

    // ---- layer 2 ----
    gemm_kernel<DH><<<GEMM_BLOCKS, 256, 0, stream>>>(h, W2, tmp, NN);
    pull_kernel<<<nblk_pull, 256, 0, stream>>>(tmp, csr_off, ew, dinv, b2, h, NN);

    // ---- layer 3 ----
    gemm_kernel<DH><<<GEMM_BLOCKS, 256, 0, stream>>>(h, W3, tmp, NN);
    pull_kernel<<<nblk_pull, 256, 0, stream>>>(tmp, csr_off, ew, dinv, b3, h, NN);

    // ---- final linear + mean pool ----
    final_pool_kernel<<<POOL_BLOCKS, 256, 0, stream>>>(h, Wl, batch, gsum, gcnt, NN);
    pool_div_kernel<<<1, 64, 0, stream>>>(gsum, gcnt, bl, out);
}